// Round 4
// baseline (497.572 us; speedup 1.0000x reference)
//
#include <hip/hip_runtime.h>
#include <math.h>

#define TPB 256
#define NBMAX 2048          // buckets of 256 nodes -> supports N <= 524288

// ---------------- bucketed CSR build ----------------

// bucket histogram (bucket = dst >> 8), LDS-aggregated
__global__ __launch_bounds__(256) void k_bhist(const int* __restrict__ ei,
                                               int* __restrict__ bhist, int E, int NB) {
    __shared__ int h[NBMAX];
    for (int i = threadIdx.x; i < NB; i += 256) h[i] = 0;
    __syncthreads();
    int stride = gridDim.x * 256;
    for (int e = blockIdx.x * 256 + threadIdx.x; e < E; e += stride)
        atomicAdd(&h[ei[E + e] >> 8], 1);
    __syncthreads();
    for (int i = threadIdx.x; i < NB; i += 256) if (h[i]) atomicAdd(&bhist[i], h[i]);
}

// exclusive scan of bucket counts; bfill = bbase; sentinel entries
__global__ __launch_bounds__(256) void k_bscan(const int* __restrict__ bhist,
                                               int* __restrict__ bbase, int* __restrict__ bfill,
                                               int* __restrict__ row_start,
                                               int NB, int N, int E) {
    __shared__ int tsum[256];
    int tid = threadIdx.x;
    int per = (NB + 255) / 256;           // <= 8
    int loc[8]; int tot = 0;
    int base = tid * per;
#pragma unroll
    for (int j = 0; j < 8; j++) {
        int i = base + j;
        int v = (j < per && i < NB) ? bhist[i] : 0;
        loc[j] = v; tot += v;
    }
    tsum[tid] = tot;
    __syncthreads();
    for (int off = 1; off < 256; off <<= 1) {
        int t = (tid >= off) ? tsum[tid - off] : 0;
        __syncthreads();
        tsum[tid] += t;
        __syncthreads();
    }
    int run = tsum[tid] - tot;
#pragma unroll
    for (int j = 0; j < 8; j++) {
        int i = base + j;
        if (j < per && i < NB) { bbase[i] = run; bfill[i] = run; run += loc[j]; }
    }
    if (tid == 0) { bbase[NB] = E; row_start[N] = E; }
}

// bin edges into bucket-contiguous ebuf: {src | dlow<<24, weight}
__global__ __launch_bounds__(256) void k_bin(const int* __restrict__ ei,
                                             const float* __restrict__ ew,
                                             int* bfill, int2* __restrict__ ebuf,
                                             int E, int NB) {
    __shared__ int h[NBMAX];
    __shared__ int gb[NBMAX];
    const int EPT = 16;
    int tid = threadIdx.x;
    int base = blockIdx.x * 256 * EPT;
    for (int i = tid; i < NB; i += 256) h[i] = 0;
    __syncthreads();
    int src[EPT]; float w[EPT]; int bkt[EPT]; int lrank[EPT];
#pragma unroll
    for (int j = 0; j < EPT; j++) {
        int e = base + j * 256 + tid;              // coalesced
        if (e < E) {
            src[j] = ei[e]; int d = ei[E + e]; w[j] = ew[e];
            int b = d >> 8;
            bkt[j] = b | ((d & 255) << 16);
            lrank[j] = atomicAdd(&h[b], 1);
        } else bkt[j] = -1;
    }
    __syncthreads();
    for (int i = tid; i < NB; i += 256) gb[i] = h[i] ? atomicAdd(&bfill[i], h[i]) : 0;
    __syncthreads();
#pragma unroll
    for (int j = 0; j < EPT; j++) {
        if (bkt[j] >= 0) {
            int b = bkt[j] & 0xFFFF, dlow = (bkt[j] >> 16) & 0xFF;
            int2 v; v.x = src[j] | (dlow << 24); v.y = __float_as_int(w[j]);
            ebuf[gb[b] + lrank[j]] = v;
        }
    }
}

// per bucket (256 nodes): counts + weight sums -> row_start, dinv, final CSR;
// fused first-layer prep: Y = dinv * X for this bucket's rows (contiguous)
__global__ __launch_bounds__(256) void k_bucket(const int2* __restrict__ ebuf,
                                                const int* __restrict__ bbase,
                                                int2* __restrict__ csr,
                                                int* __restrict__ row_start,
                                                float* __restrict__ dinv,
                                                const float4* __restrict__ X4,
                                                float4* __restrict__ Y4,
                                                int N, int E) {
    __shared__ int lcnt[256];
    __shared__ float wsum[256];
    __shared__ int lstart[256];
    __shared__ int sc[256];
    __shared__ float sdinv[256];
    int b = blockIdx.x, tid = threadIdx.x;
    int beg = bbase[b], end = bbase[b + 1];
    lcnt[tid] = 0; wsum[tid] = 0.f;
    __syncthreads();
    for (int i = beg + tid; i < end; i += 256) {
        int2 v = ebuf[i];
        int dlow = ((unsigned)v.x) >> 24;
        atomicAdd(&lcnt[dlow], 1);
        atomicAdd(&wsum[dlow], __int_as_float(v.y));
    }
    __syncthreads();
    int myc = lcnt[tid];
    sc[tid] = myc;
    __syncthreads();
    for (int off = 1; off < 256; off <<= 1) {
        int t = (tid >= off) ? sc[tid - off] : 0;
        __syncthreads();
        sc[tid] += t;
        __syncthreads();
    }
    lstart[tid] = sc[tid] - myc;
    int node = (b << 8) + tid;
    float dv = rsqrtf(1.0f + wsum[tid]);          // self-loop weight 1; deg >= 1
    sdinv[tid] = dv;
    if (node < N) {
        row_start[node] = beg + sc[tid] - myc;
        dinv[node] = dv;
    }
    lcnt[tid] = 0;
    __syncthreads();
    for (int i = beg + tid; i < end; i += 256) {
        int2 v = ebuf[i];
        int dlow = ((unsigned)v.x) >> 24;
        int pos = lstart[dlow] + atomicAdd(&lcnt[dlow], 1);
        int2 o; o.x = v.x & 0x00FFFFFF; o.y = v.y;
        csr[beg + pos] = o;                        // confined to 32KB bucket segment
    }
    // fused prep: Y rows for this bucket (8 float4 per node, contiguous)
    int nNodes = N - (b << 8); if (nNodes > 256) nNodes = 256;
    int limit = nNodes * 8;
    size_t base4 = ((size_t)b << 8) * 8;
    for (int i = tid; i < limit; i += 256) {
        float4 v = X4[base4 + i];
        float d = sdinv[i >> 3];
        float4 o; o.x = v.x * d; o.y = v.y * d; o.z = v.z * d; o.w = v.w * d;
        Y4[base4 + i] = o;
    }
}

// ---------------- per-layer compute ----------------

// AX[d,:] = dinv[d] * (Y[d,:] + sum_e w_e * Y[src_e,:])
// one wave per node; 16 lanes x float2 cover the row; 4 quarter-waves = 4 edges
// per memory instruction; 2-deep software pipeline -> 8 edges in flight / wave
__global__ __launch_bounds__(256) void k_gather(const float2* __restrict__ Y2,
                                                const int* __restrict__ row_start,
                                                const int2* __restrict__ csr,
                                                const float* __restrict__ dinv,
                                                float2* __restrict__ AX2, int N) {
    int wid = (blockIdx.x * blockDim.x + threadIdx.x) >> 6;
    if (wid >= N) return;
    int lane = threadIdx.x & 63;
    int q = lane >> 4, c2 = lane & 15;
    int rs = row_start[wid], re = row_start[wid + 1];
    float2 acc1, acc2;
    if (q == 0) acc1 = Y2[(size_t)wid * 16 + c2];       // self-loop once
    else { acc1.x = 0.f; acc1.y = 0.f; }
    acc2.x = 0.f; acc2.y = 0.f;
    int e = rs + q;
    int2 p0, p1;
    if (e < re) p0 = csr[e];
    if (e + 4 < re) p1 = csr[e + 4];
    while (e + 4 < re) {
        int2 a = p0, b = p1;
        if (e + 8 < re)  p0 = csr[e + 8];
        if (e + 12 < re) p1 = csr[e + 12];
        float2 ya = Y2[(size_t)a.x * 16 + c2];
        float2 yb = Y2[(size_t)b.x * 16 + c2];
        float wa = __int_as_float(a.y), wb = __int_as_float(b.y);
        acc1.x += wa * ya.x; acc1.y += wa * ya.y;
        acc2.x += wb * yb.x; acc2.y += wb * yb.y;
        e += 8;
    }
    if (e < re) {
        float2 ya = Y2[(size_t)p0.x * 16 + c2];
        float w = __int_as_float(p0.y);
        acc1.x += w * ya.x; acc1.y += w * ya.y;
    }
    acc1.x += acc2.x; acc1.y += acc2.y;
    acc1.x += __shfl_xor(acc1.x, 16); acc1.y += __shfl_xor(acc1.y, 16);
    acc1.x += __shfl_xor(acc1.x, 32); acc1.y += __shfl_xor(acc1.y, 32);
    if (lane < 16) {
        float di = dinv[wid];
        float2 o; o.x = acc1.x * di; o.y = acc1.y * di;
        AX2[(size_t)wid * 16 + c2] = o;
    }
}

// G = AX @ [W_I|W_T|W_O] + biases; gates fused in-register (no Gs LDS)
__global__ __launch_bounds__(256) void k_gates(const float* __restrict__ AX,
                                               const float* __restrict__ cw,
                                               const float* __restrict__ cb,
                                               const float* __restrict__ wc,
                                               const float* __restrict__ bg,
                                               const float* __restrict__ dinv,
                                               float* __restrict__ outRaw,
                                               float* __restrict__ outY,
                                               int N, int l, int isLast) {
    __shared__ float Ws[32][96];                   // [k][gate*32 + c]
    __shared__ float Xs[32][33];
    int tid = threadIdx.x;
    for (int i = tid; i < 3072; i += 256) {
        int k = i / 96, ccol = i - k * 96;
        int g = ccol >> 5, o = ccol & 31;
        int j = (g == 0) ? 0 : ((g == 1) ? 4 : 6); // I, T, O convs on x
        Ws[k][ccol] = cw[(((l * 8 + j) * 32) + k) * 32 + o];
    }
    int row0 = blockIdx.x * 32;
    for (int i = tid; i < 1024; i += 256) {
        int r = i >> 5, k = i & 31; int gr = row0 + r;
        Xs[r][k] = (gr < N) ? AX[(size_t)gr * 32 + k] : 0.f;
    }
    __syncthreads();
    int r = tid >> 3, g8 = tid & 7;                // 4 channels: c = g8*4 + cc
    float aI[4] = {0,0,0,0}, aT[4] = {0,0,0,0}, aO[4] = {0,0,0,0};
#pragma unroll
    for (int k = 0; k < 32; k++) {
        float xv = Xs[r][k];
#pragma unroll
        for (int cc = 0; cc < 4; cc++) {
            int c = g8 * 4 + cc;
            aI[cc] += xv * Ws[k][c];
            aT[cc] += xv * Ws[k][32 + c];
            aO[cc] += xv * Ws[k][64 + c];
        }
    }
    int gn = row0 + r;
    if (gn < N) {
        float di = dinv[gn];
#pragma unroll
        for (int cc = 0; cc < 4; cc++) {
            int c = g8 * 4 + cc;
            float bI = cb[((l * 8 + 0) * 32) + c] + cb[((l * 8 + 1) * 32) + c] + bg[((l * 4 + 0) * 32) + c];
            float bT = cb[((l * 8 + 4) * 32) + c] + cb[((l * 8 + 5) * 32) + c] + bg[((l * 4 + 2) * 32) + c];
            float bO = cb[((l * 8 + 6) * 32) + c] + cb[((l * 8 + 7) * 32) + c] + bg[((l * 4 + 3) * 32) + c];
            float I = 1.f / (1.f + expf(-(aI[cc] + bI)));
            float T = tanhf(aT[cc] + bT);
            float C = I * T;                       // C_old = 0, F-gate dead
            float O = 1.f / (1.f + expf(-(aO[cc] + wc[((l * 3 + 2) * 32) + c] * C + bO)));
            float val = O * tanhf(C);
            if (isLast) outRaw[(size_t)gn * 32 + c] = val;
            else        outY[(size_t)gn * 32 + c] = di * val;
        }
    }
}

extern "C" void kernel_launch(void* const* d_in, const int* in_sizes, int n_in,
                              void* d_out, int out_size, void* d_ws, size_t ws_size,
                              hipStream_t stream) {
    const float* X  = (const float*)d_in[0];
    const int*   ei = (const int*)d_in[1];
    const float* ew = (const float*)d_in[2];
    const float* cw = (const float*)d_in[3];
    const float* cb = (const float*)d_in[4];
    const float* wc = (const float*)d_in[5];
    const float* bg = (const float*)d_in[6];
    int N = in_sizes[0] / 32;
    int E = in_sizes[2];
    int L = in_sizes[3] / (8 * 32 * 32);
    float* out = (float*)d_out;
    int NB = (N + 255) >> 8;

    char* p = (char*)d_ws;
    auto alloc = [&](size_t bytes) -> char* {
        char* r = p; p += (bytes + 255) & ~(size_t)255; return r;
    };
    int*   bhist     = (int*)alloc((size_t)NB * 4);
    int*   bbase     = (int*)alloc((size_t)(NB + 1) * 4);
    int*   bfill     = (int*)alloc((size_t)NB * 4);
    int*   row_start = (int*)alloc((size_t)(N + 1) * 4);
    float* dinv      = (float*)alloc((size_t)N * 4);
    int2*  ebuf      = (int2*)alloc((size_t)E * 8);
    int2*  csr       = (int2*)alloc((size_t)E * 8);
    float* Y         = (float*)alloc((size_t)N * 32 * 4);
    float* AX        = (float*)alloc((size_t)N * 32 * 4);

    hipMemsetAsync(bhist, 0, (size_t)NB * 4, stream);
    k_bhist<<<512, 256, 0, stream>>>(ei, bhist, E, NB);
    k_bscan<<<1, 256, 0, stream>>>(bhist, bbase, bfill, row_start, NB, N, E);
    int nBin = (E + 4095) / 4096;
    k_bin<<<nBin, 256, 0, stream>>>(ei, ew, bfill, ebuf, E, NB);
    k_bucket<<<NB, 256, 0, stream>>>(ebuf, bbase, csr, row_start, dinv,
                                     (const float4*)X, (float4*)Y, N, E);

    for (int l = 0; l < L; l++) {
        k_gather<<<(N + 3) / 4, 256, 0, stream>>>((const float2*)Y, row_start, csr,
                                                  dinv, (float2*)AX, N);
        k_gates<<<(N + 31) / 32, 256, 0, stream>>>(AX, cw, cb, wc, bg, dinv,
                                                   out, Y, N, l, l == L - 1);
    }
}

// Round 5
// 312.112 us; speedup vs baseline: 1.5942x; 1.5942x over previous
//
#include <hip/hip_runtime.h>
#include <math.h>

#define TPB 256
#define NBMAX 2048          // buckets of 256 nodes -> supports N <= 524288

// ---------------- bucketed CSR build ----------------

// bucket histogram (bucket = dst >> 8), LDS-aggregated
__global__ __launch_bounds__(256) void k_bhist(const int* __restrict__ ei,
                                               int* __restrict__ bhist, int E, int NB) {
    __shared__ int h[NBMAX];
    for (int i = threadIdx.x; i < NB; i += 256) h[i] = 0;
    __syncthreads();
    int stride = gridDim.x * 256;
    for (int e = blockIdx.x * 256 + threadIdx.x; e < E; e += stride)
        atomicAdd(&h[ei[E + e] >> 8], 1);
    __syncthreads();
    for (int i = threadIdx.x; i < NB; i += 256) if (h[i]) atomicAdd(&bhist[i], h[i]);
}

// exclusive scan of bucket counts; bfill = bbase; sentinel entries
__global__ __launch_bounds__(256) void k_bscan(const int* __restrict__ bhist,
                                               int* __restrict__ bbase, int* __restrict__ bfill,
                                               int* __restrict__ row_start,
                                               int NB, int N, int E) {
    __shared__ int tsum[256];
    int tid = threadIdx.x;
    int per = (NB + 255) / 256;           // <= 8
    int loc[8]; int tot = 0;
    int base = tid * per;
#pragma unroll
    for (int j = 0; j < 8; j++) {
        int i = base + j;
        int v = (j < per && i < NB) ? bhist[i] : 0;
        loc[j] = v; tot += v;
    }
    tsum[tid] = tot;
    __syncthreads();
    for (int off = 1; off < 256; off <<= 1) {
        int t = (tid >= off) ? tsum[tid - off] : 0;
        __syncthreads();
        tsum[tid] += t;
        __syncthreads();
    }
    int run = tsum[tid] - tot;
#pragma unroll
    for (int j = 0; j < 8; j++) {
        int i = base + j;
        if (j < per && i < NB) { bbase[i] = run; bfill[i] = run; run += loc[j]; }
    }
    if (tid == 0) { bbase[NB] = E; row_start[N] = E; }
}

// bin edges into bucket-contiguous ebuf: {src | dlow<<24, weight}
__global__ __launch_bounds__(256) void k_bin(const int* __restrict__ ei,
                                             const float* __restrict__ ew,
                                             int* bfill, int2* __restrict__ ebuf,
                                             int E, int NB) {
    __shared__ int h[NBMAX];
    __shared__ int gb[NBMAX];
    const int EPT = 16;
    int tid = threadIdx.x;
    int base = blockIdx.x * 256 * EPT;
    for (int i = tid; i < NB; i += 256) h[i] = 0;
    __syncthreads();
    int src[EPT]; float w[EPT]; int bkt[EPT]; int lrank[EPT];
#pragma unroll
    for (int j = 0; j < EPT; j++) {
        int e = base + j * 256 + tid;              // coalesced
        if (e < E) {
            src[j] = ei[e]; int d = ei[E + e]; w[j] = ew[e];
            int b = d >> 8;
            bkt[j] = b | ((d & 255) << 16);
            lrank[j] = atomicAdd(&h[b], 1);
        } else bkt[j] = -1;
    }
    __syncthreads();
    for (int i = tid; i < NB; i += 256) gb[i] = h[i] ? atomicAdd(&bfill[i], h[i]) : 0;
    __syncthreads();
#pragma unroll
    for (int j = 0; j < EPT; j++) {
        if (bkt[j] >= 0) {
            int b = bkt[j] & 0xFFFF, dlow = (bkt[j] >> 16) & 0xFF;
            int2 v; v.x = src[j] | (dlow << 24); v.y = __float_as_int(w[j]);
            ebuf[gb[b] + lrank[j]] = v;
        }
    }
}

// per bucket (256 nodes): counts + weight sums -> row_start, dinv, final CSR;
// fused first-layer prep: Y = dinv * X for this bucket's rows (contiguous)
__global__ __launch_bounds__(256) void k_bucket(const int2* __restrict__ ebuf,
                                                const int* __restrict__ bbase,
                                                int2* __restrict__ csr,
                                                int* __restrict__ row_start,
                                                float* __restrict__ dinv,
                                                const float4* __restrict__ X4,
                                                float4* __restrict__ Y4,
                                                int N, int E) {
    __shared__ int lcnt[256];
    __shared__ float wsum[256];
    __shared__ int lstart[256];
    __shared__ int sc[256];
    __shared__ float sdinv[256];
    int b = blockIdx.x, tid = threadIdx.x;
    int beg = bbase[b], end = bbase[b + 1];
    lcnt[tid] = 0; wsum[tid] = 0.f;
    __syncthreads();
    for (int i = beg + tid; i < end; i += 256) {
        int2 v = ebuf[i];
        int dlow = ((unsigned)v.x) >> 24;
        atomicAdd(&lcnt[dlow], 1);
        atomicAdd(&wsum[dlow], __int_as_float(v.y));
    }
    __syncthreads();
    int myc = lcnt[tid];
    sc[tid] = myc;
    __syncthreads();
    for (int off = 1; off < 256; off <<= 1) {
        int t = (tid >= off) ? sc[tid - off] : 0;
        __syncthreads();
        sc[tid] += t;
        __syncthreads();
    }
    lstart[tid] = sc[tid] - myc;
    int node = (b << 8) + tid;
    float dv = rsqrtf(1.0f + wsum[tid]);          // self-loop weight 1; deg >= 1
    sdinv[tid] = dv;
    if (node < N) {
        row_start[node] = beg + sc[tid] - myc;
        dinv[node] = dv;
    }
    lcnt[tid] = 0;
    __syncthreads();
    for (int i = beg + tid; i < end; i += 256) {
        int2 v = ebuf[i];
        int dlow = ((unsigned)v.x) >> 24;
        int pos = lstart[dlow] + atomicAdd(&lcnt[dlow], 1);
        int2 o; o.x = v.x & 0x00FFFFFF; o.y = v.y;
        csr[beg + pos] = o;                        // confined to 32KB bucket segment
    }
    // fused prep: Y rows for this bucket (8 float4 per node, contiguous)
    int nNodes = N - (b << 8); if (nNodes > 256) nNodes = 256;
    int limit = nNodes * 8;
    size_t base4 = ((size_t)b << 8) * 8;
    for (int i = tid; i < limit; i += 256) {
        float4 v = X4[base4 + i];
        float d = sdinv[i >> 3];
        float4 o; o.x = v.x * d; o.y = v.y * d; o.z = v.z * d; o.w = v.w * d;
        Y4[base4 + i] = o;
    }
}

// ---------------- per-layer compute ----------------

// AX[d,:] = dinv[d] * (Y[d,:] + sum_e w_e * Y[src_e,:])
// one wave per node; 16 lanes x float2 cover the row; 4 quarter-waves = 4 edges
// per memory instruction; 2-deep software pipeline -> 8 edges in flight / wave
__global__ __launch_bounds__(256) void k_gather(const float2* __restrict__ Y2,
                                                const int* __restrict__ row_start,
                                                const int2* __restrict__ csr,
                                                const float* __restrict__ dinv,
                                                float2* __restrict__ AX2, int N) {
    int wid = (blockIdx.x * blockDim.x + threadIdx.x) >> 6;
    if (wid >= N) return;
    int lane = threadIdx.x & 63;
    int q = lane >> 4, c2 = lane & 15;
    int rs = row_start[wid], re = row_start[wid + 1];
    float2 acc1, acc2;
    if (q == 0) acc1 = Y2[(size_t)wid * 16 + c2];       // self-loop once
    else { acc1.x = 0.f; acc1.y = 0.f; }
    acc2.x = 0.f; acc2.y = 0.f;
    int e = rs + q;
    int2 p0, p1;
    if (e < re) p0 = csr[e];
    if (e + 4 < re) p1 = csr[e + 4];
    while (e + 4 < re) {
        int2 a = p0, b = p1;
        if (e + 8 < re)  p0 = csr[e + 8];
        if (e + 12 < re) p1 = csr[e + 12];
        float2 ya = Y2[(size_t)a.x * 16 + c2];
        float2 yb = Y2[(size_t)b.x * 16 + c2];
        float wa = __int_as_float(a.y), wb = __int_as_float(b.y);
        acc1.x += wa * ya.x; acc1.y += wa * ya.y;
        acc2.x += wb * yb.x; acc2.y += wb * yb.y;
        e += 8;
    }
    if (e < re) {
        float2 ya = Y2[(size_t)p0.x * 16 + c2];
        float w = __int_as_float(p0.y);
        acc1.x += w * ya.x; acc1.y += w * ya.y;
    }
    acc1.x += acc2.x; acc1.y += acc2.y;
    acc1.x += __shfl_xor(acc1.x, 16); acc1.y += __shfl_xor(acc1.y, 16);
    acc1.x += __shfl_xor(acc1.x, 32); acc1.y += __shfl_xor(acc1.y, 32);
    if (lane < 16) {
        float di = dinv[wid];
        float2 o; o.x = acc1.x * di; o.y = acc1.y * di;
        AX2[(size_t)wid * 16 + c2] = o;
    }
}

// G = AX @ [W_I|W_T|W_O] + biases; Gs staged through LDS (round-3 design:
// VGPR ~48, occupancy-friendly — the in-register variant hit 216 VGPR / 10% occ)
__global__ __launch_bounds__(256) void k_gates(const float* __restrict__ AX,
                                               const float* __restrict__ cw,
                                               const float* __restrict__ cb,
                                               const float* __restrict__ wc,
                                               const float* __restrict__ bg,
                                               const float* __restrict__ dinv,
                                               float* __restrict__ outRaw,
                                               float* __restrict__ outY,
                                               int N, int l, int isLast) {
    __shared__ float Ws[32][96];
    __shared__ float Xs[32][33];
    __shared__ float Gs[32][96];
    int tid = threadIdx.x;
    for (int i = tid; i < 3072; i += 256) {
        int k = i / 96, ccol = i - k * 96;
        int g = ccol >> 5, o = ccol & 31;
        int j = (g == 0) ? 0 : ((g == 1) ? 4 : 6); // I, T, O convs on x
        Ws[k][ccol] = cw[(((l * 8 + j) * 32) + k) * 32 + o];
    }
    int row0 = blockIdx.x * 32;
    for (int i = tid; i < 1024; i += 256) {
        int r = i >> 5, k = i & 31; int gr = row0 + r;
        Xs[r][k] = (gr < N) ? AX[(size_t)gr * 32 + k] : 0.f;
    }
    __syncthreads();
    {
        int r = tid >> 3, g8 = tid & 7;
        float acc[12];
#pragma unroll
        for (int j = 0; j < 12; j++) acc[j] = 0.f;
#pragma unroll
        for (int k = 0; k < 32; k++) {
            float xv = Xs[r][k];
#pragma unroll
            for (int j = 0; j < 12; j++) acc[j] += xv * Ws[k][g8 * 12 + j];
        }
#pragma unroll
        for (int j = 0; j < 12; j++) Gs[r][g8 * 12 + j] = acc[j];
    }
    __syncthreads();
    for (int i = tid; i < 1024; i += 256) {
        int r = i >> 5, c = i & 31;
        int gn = row0 + r;
        if (gn >= N) continue;
        float bI = cb[((l * 8 + 0) * 32) + c] + cb[((l * 8 + 1) * 32) + c] + bg[((l * 4 + 0) * 32) + c];
        float bT = cb[((l * 8 + 4) * 32) + c] + cb[((l * 8 + 5) * 32) + c] + bg[((l * 4 + 2) * 32) + c];
        float bO = cb[((l * 8 + 6) * 32) + c] + cb[((l * 8 + 7) * 32) + c] + bg[((l * 4 + 3) * 32) + c];
        float I = 1.f / (1.f + expf(-(Gs[r][c] + bI)));
        float T = tanhf(Gs[r][32 + c] + bT);
        float C = I * T;                          // C_old = 0, F-gate dead
        float O = 1.f / (1.f + expf(-(Gs[r][64 + c] + wc[((l * 3 + 2) * 32) + c] * C + bO)));
        float val = O * tanhf(C);
        if (isLast) outRaw[(size_t)gn * 32 + c] = val;
        else        outY[(size_t)gn * 32 + c] = dinv[gn] * val;
    }
}

extern "C" void kernel_launch(void* const* d_in, const int* in_sizes, int n_in,
                              void* d_out, int out_size, void* d_ws, size_t ws_size,
                              hipStream_t stream) {
    const float* X  = (const float*)d_in[0];
    const int*   ei = (const int*)d_in[1];
    const float* ew = (const float*)d_in[2];
    const float* cw = (const float*)d_in[3];
    const float* cb = (const float*)d_in[4];
    const float* wc = (const float*)d_in[5];
    const float* bg = (const float*)d_in[6];
    int N = in_sizes[0] / 32;
    int E = in_sizes[2];
    int L = in_sizes[3] / (8 * 32 * 32);
    float* out = (float*)d_out;
    int NB = (N + 255) >> 8;

    char* p = (char*)d_ws;
    auto alloc = [&](size_t bytes) -> char* {
        char* r = p; p += (bytes + 255) & ~(size_t)255; return r;
    };
    int*   bhist     = (int*)alloc((size_t)NB * 4);
    int*   bbase     = (int*)alloc((size_t)(NB + 1) * 4);
    int*   bfill     = (int*)alloc((size_t)NB * 4);
    int*   row_start = (int*)alloc((size_t)(N + 1) * 4);
    float* dinv      = (float*)alloc((size_t)N * 4);
    int2*  ebuf      = (int2*)alloc((size_t)E * 8);
    int2*  csr       = (int2*)alloc((size_t)E * 8);
    float* Y         = (float*)alloc((size_t)N * 32 * 4);
    float* AX        = (float*)alloc((size_t)N * 32 * 4);

    hipMemsetAsync(bhist, 0, (size_t)NB * 4, stream);
    k_bhist<<<512, 256, 0, stream>>>(ei, bhist, E, NB);
    k_bscan<<<1, 256, 0, stream>>>(bhist, bbase, bfill, row_start, NB, N, E);
    int nBin = (E + 4095) / 4096;
    k_bin<<<nBin, 256, 0, stream>>>(ei, ew, bfill, ebuf, E, NB);
    k_bucket<<<NB, 256, 0, stream>>>(ebuf, bbase, csr, row_start, dinv,
                                     (const float4*)X, (float4*)Y, N, E);

    for (int l = 0; l < L; l++) {
        k_gather<<<(N + 3) / 4, 256, 0, stream>>>((const float2*)Y, row_start, csr,
                                                  dinv, (float2*)AX, N);
        k_gates<<<(N + 31) / 32, 256, 0, stream>>>(AX, cw, cb, wc, bg, dinv,
                                                   out, Y, N, l, l == L - 1);
    }
}

// Round 6
// 284.329 us; speedup vs baseline: 1.7500x; 1.0977x over previous
//
#include <hip/hip_runtime.h>
#include <math.h>

#define TPB 256
#define NBMAX 2048          // buckets of 256 nodes -> supports N <= 524288

__device__ __forceinline__ float fsig(float x) {
    return __builtin_amdgcn_rcpf(1.f + __expf(-x));   // abs err ~1e-7; x->-inf => 0
}
__device__ __forceinline__ float ftanh(float x) {
    float t = __expf(2.f * fabsf(x));                  // t -> inf => r -> 1
    float r = 1.f - 2.f * __builtin_amdgcn_rcpf(t + 1.f);
    return copysignf(r, x);
}

// ---------------- bucketed CSR build ----------------

// bucket histogram (bucket = dst >> 8), LDS-aggregated
__global__ __launch_bounds__(256) void k_bhist(const int* __restrict__ ei,
                                               int* __restrict__ bhist, int E, int NB) {
    __shared__ int h[NBMAX];
    for (int i = threadIdx.x; i < NB; i += 256) h[i] = 0;
    __syncthreads();
    int stride = gridDim.x * 256;
    for (int e = blockIdx.x * 256 + threadIdx.x; e < E; e += stride)
        atomicAdd(&h[ei[E + e] >> 8], 1);
    __syncthreads();
    for (int i = threadIdx.x; i < NB; i += 256) if (h[i]) atomicAdd(&bhist[i], h[i]);
}

// exclusive scan of bucket counts; bfill = bbase; sentinel entries
__global__ __launch_bounds__(256) void k_bscan(const int* __restrict__ bhist,
                                               int* __restrict__ bbase, int* __restrict__ bfill,
                                               int* __restrict__ row_start,
                                               int NB, int N, int E) {
    __shared__ int tsum[256];
    int tid = threadIdx.x;
    int per = (NB + 255) / 256;           // <= 8
    int loc[8]; int tot = 0;
    int base = tid * per;
#pragma unroll
    for (int j = 0; j < 8; j++) {
        int i = base + j;
        int v = (j < per && i < NB) ? bhist[i] : 0;
        loc[j] = v; tot += v;
    }
    tsum[tid] = tot;
    __syncthreads();
    for (int off = 1; off < 256; off <<= 1) {
        int t = (tid >= off) ? tsum[tid - off] : 0;
        __syncthreads();
        tsum[tid] += t;
        __syncthreads();
    }
    int run = tsum[tid] - tot;
#pragma unroll
    for (int j = 0; j < 8; j++) {
        int i = base + j;
        if (j < per && i < NB) { bbase[i] = run; bfill[i] = run; run += loc[j]; }
    }
    if (tid == 0) { bbase[NB] = E; row_start[N] = E; }
}

// bin edges into bucket-contiguous ebuf: {src | dlow<<24, weight}
__global__ __launch_bounds__(256) void k_bin(const int* __restrict__ ei,
                                             const float* __restrict__ ew,
                                             int* bfill, int2* __restrict__ ebuf,
                                             int E, int NB) {
    __shared__ int h[NBMAX];
    __shared__ int gb[NBMAX];
    const int EPT = 16;
    int tid = threadIdx.x;
    int base = blockIdx.x * 256 * EPT;
    for (int i = tid; i < NB; i += 256) h[i] = 0;
    __syncthreads();
    int src[EPT]; float w[EPT]; int bkt[EPT]; int lrank[EPT];
#pragma unroll
    for (int j = 0; j < EPT; j++) {
        int e = base + j * 256 + tid;              // coalesced
        if (e < E) {
            src[j] = ei[e]; int d = ei[E + e]; w[j] = ew[e];
            int b = d >> 8;
            bkt[j] = b | ((d & 255) << 16);
            lrank[j] = atomicAdd(&h[b], 1);
        } else bkt[j] = -1;
    }
    __syncthreads();
    for (int i = tid; i < NB; i += 256) gb[i] = h[i] ? atomicAdd(&bfill[i], h[i]) : 0;
    __syncthreads();
#pragma unroll
    for (int j = 0; j < EPT; j++) {
        if (bkt[j] >= 0) {
            int b = bkt[j] & 0xFFFF, dlow = (bkt[j] >> 16) & 0xFF;
            int2 v; v.x = src[j] | (dlow << 24); v.y = __float_as_int(w[j]);
            ebuf[gb[b] + lrank[j]] = v;
        }
    }
}

// per bucket (256 nodes): counts + weight sums -> row_start, dinv, final CSR;
// fused first-layer prep: Y = dinv * X for this bucket's rows (contiguous)
__global__ __launch_bounds__(256) void k_bucket(const int2* __restrict__ ebuf,
                                                const int* __restrict__ bbase,
                                                int2* __restrict__ csr,
                                                int* __restrict__ row_start,
                                                float* __restrict__ dinv,
                                                const float4* __restrict__ X4,
                                                float4* __restrict__ Y4,
                                                int N, int E) {
    __shared__ int lcnt[256];
    __shared__ float wsum[256];
    __shared__ int lstart[256];
    __shared__ int sc[256];
    __shared__ float sdinv[256];
    int b = blockIdx.x, tid = threadIdx.x;
    int beg = bbase[b], end = bbase[b + 1];
    lcnt[tid] = 0; wsum[tid] = 0.f;
    __syncthreads();
    for (int i = beg + tid; i < end; i += 256) {
        int2 v = ebuf[i];
        int dlow = ((unsigned)v.x) >> 24;
        atomicAdd(&lcnt[dlow], 1);
        atomicAdd(&wsum[dlow], __int_as_float(v.y));
    }
    __syncthreads();
    int myc = lcnt[tid];
    sc[tid] = myc;
    __syncthreads();
    for (int off = 1; off < 256; off <<= 1) {
        int t = (tid >= off) ? sc[tid - off] : 0;
        __syncthreads();
        sc[tid] += t;
        __syncthreads();
    }
    lstart[tid] = sc[tid] - myc;
    int node = (b << 8) + tid;
    float dv = rsqrtf(1.0f + wsum[tid]);          // self-loop weight 1; deg >= 1
    sdinv[tid] = dv;
    if (node < N) {
        row_start[node] = beg + sc[tid] - myc;
        dinv[node] = dv;
    }
    lcnt[tid] = 0;
    __syncthreads();
    for (int i = beg + tid; i < end; i += 256) {
        int2 v = ebuf[i];
        int dlow = ((unsigned)v.x) >> 24;
        int pos = lstart[dlow] + atomicAdd(&lcnt[dlow], 1);
        int2 o; o.x = v.x & 0x00FFFFFF; o.y = v.y;
        csr[beg + pos] = o;                        // confined to 32KB bucket segment
    }
    // fused prep: Y rows for this bucket (8 float4 per node, contiguous)
    int nNodes = N - (b << 8); if (nNodes > 256) nNodes = 256;
    int limit = nNodes * 8;
    size_t base4 = ((size_t)b << 8) * 8;
    for (int i = tid; i < limit; i += 256) {
        float4 v = X4[base4 + i];
        float d = sdinv[i >> 3];
        float4 o; o.x = v.x * d; o.y = v.y * d; o.z = v.z * d; o.w = v.w * d;
        Y4[base4 + i] = o;
    }
}

// ---------------- per-layer compute ----------------

// AX[d,:] = dinv[d] * (Y[d,:] + sum_e w_e * Y[src_e,:])
// one wave per node; 8 lanes x float4 cover the 128B row; 8 eighth-waves =
// 8 edges per memory instruction; 2-deep pipeline -> 16 edges in flight / wave
__global__ __launch_bounds__(256) void k_gather(const float4* __restrict__ Y4,
                                                const int* __restrict__ row_start,
                                                const int2* __restrict__ csr,
                                                const float* __restrict__ dinv,
                                                float4* __restrict__ AX4, int N) {
    int wid = (blockIdx.x * blockDim.x + threadIdx.x) >> 6;
    if (wid >= N) return;
    int lane = threadIdx.x & 63;
    int q = lane >> 3, c4 = lane & 7;
    int rs = row_start[wid], re = row_start[wid + 1];
    float4 acc1, acc2;
    if (q == 0) acc1 = Y4[(size_t)wid * 8 + c4];        // self-loop once
    else { acc1.x = 0.f; acc1.y = 0.f; acc1.z = 0.f; acc1.w = 0.f; }
    acc2.x = 0.f; acc2.y = 0.f; acc2.z = 0.f; acc2.w = 0.f;
    int e = rs + q;
    int2 p0, p1;
    if (e < re) p0 = csr[e];
    if (e + 8 < re) p1 = csr[e + 8];
    while (e + 8 < re) {
        int2 a = p0, b = p1;
        if (e + 16 < re) p0 = csr[e + 16];
        if (e + 24 < re) p1 = csr[e + 24];
        float4 ya = Y4[(size_t)a.x * 8 + c4];
        float4 yb = Y4[(size_t)b.x * 8 + c4];
        float wa = __int_as_float(a.y), wb = __int_as_float(b.y);
        acc1.x += wa * ya.x; acc1.y += wa * ya.y; acc1.z += wa * ya.z; acc1.w += wa * ya.w;
        acc2.x += wb * yb.x; acc2.y += wb * yb.y; acc2.z += wb * yb.z; acc2.w += wb * yb.w;
        e += 16;
    }
    if (e < re) {
        float4 ya = Y4[(size_t)p0.x * 8 + c4];
        float w = __int_as_float(p0.y);
        acc1.x += w * ya.x; acc1.y += w * ya.y; acc1.z += w * ya.z; acc1.w += w * ya.w;
    }
    acc1.x += acc2.x; acc1.y += acc2.y; acc1.z += acc2.z; acc1.w += acc2.w;
#pragma unroll
    for (int off = 8; off <= 32; off <<= 1) {
        acc1.x += __shfl_xor(acc1.x, off);
        acc1.y += __shfl_xor(acc1.y, off);
        acc1.z += __shfl_xor(acc1.z, off);
        acc1.w += __shfl_xor(acc1.w, off);
    }
    if (lane < 8) {
        float di = dinv[wid];
        float4 o; o.x = acc1.x * di; o.y = acc1.y * di; o.z = acc1.z * di; o.w = acc1.w * di;
        AX4[(size_t)wid * 8 + c4] = o;
    }
}

// G = AX @ [W_I|W_T|W_O]; Gs staged through LDS (48-VGPR structure);
// biases/peephole hoisted to LDS; fast sigmoid/tanh via v_exp + v_rcp
__global__ __launch_bounds__(256) void k_gates(const float* __restrict__ AX,
                                               const float* __restrict__ cw,
                                               const float* __restrict__ cb,
                                               const float* __restrict__ wc,
                                               const float* __restrict__ bg,
                                               const float* __restrict__ dinv,
                                               float* __restrict__ outRaw,
                                               float* __restrict__ outY,
                                               int N, int l, int isLast) {
    __shared__ float Ws[32][96];
    __shared__ float Xs[32][33];
    __shared__ float Gs[32][96];
    __shared__ float bS[96];                       // bI | bT | bO (summed)
    __shared__ float wcs[32];
    int tid = threadIdx.x;
    for (int i = tid; i < 3072; i += 256) {
        int k = i / 96, ccol = i - k * 96;
        int g = ccol >> 5, o = ccol & 31;
        int j = (g == 0) ? 0 : ((g == 1) ? 4 : 6); // I, T, O convs on x
        Ws[k][ccol] = cw[(((l * 8 + j) * 32) + k) * 32 + o];
    }
    if (tid < 32) {
        int c = tid;
        bS[c]      = cb[((l * 8 + 0) * 32) + c] + cb[((l * 8 + 1) * 32) + c] + bg[((l * 4 + 0) * 32) + c];
        bS[32 + c] = cb[((l * 8 + 4) * 32) + c] + cb[((l * 8 + 5) * 32) + c] + bg[((l * 4 + 2) * 32) + c];
        bS[64 + c] = cb[((l * 8 + 6) * 32) + c] + cb[((l * 8 + 7) * 32) + c] + bg[((l * 4 + 3) * 32) + c];
        wcs[c]     = wc[((l * 3 + 2) * 32) + c];
    }
    int row0 = blockIdx.x * 32;
    for (int i = tid; i < 1024; i += 256) {
        int r = i >> 5, k = i & 31; int gr = row0 + r;
        Xs[r][k] = (gr < N) ? AX[(size_t)gr * 32 + k] : 0.f;
    }
    __syncthreads();
    {
        int r = tid >> 3, g8 = tid & 7;
        float acc[12];
#pragma unroll
        for (int j = 0; j < 12; j++) acc[j] = 0.f;
#pragma unroll
        for (int k = 0; k < 32; k++) {
            float xv = Xs[r][k];
#pragma unroll
            for (int j = 0; j < 12; j++) acc[j] += xv * Ws[k][g8 * 12 + j];
        }
#pragma unroll
        for (int j = 0; j < 12; j++) Gs[r][g8 * 12 + j] = acc[j];
    }
    __syncthreads();
    for (int i = tid; i < 1024; i += 256) {
        int r = i >> 5, c = i & 31;
        int gn = row0 + r;
        if (gn >= N) continue;
        float I = fsig(Gs[r][c] + bS[c]);
        float T = ftanh(Gs[r][32 + c] + bS[32 + c]);
        float C = I * T;                          // C_old = 0, F-gate dead
        float O = fsig(Gs[r][64 + c] + wcs[c] * C + bS[64 + c]);
        float val = O * ftanh(C);
        if (isLast) outRaw[(size_t)gn * 32 + c] = val;
        else        outY[(size_t)gn * 32 + c] = dinv[gn] * val;
    }
}

extern "C" void kernel_launch(void* const* d_in, const int* in_sizes, int n_in,
                              void* d_out, int out_size, void* d_ws, size_t ws_size,
                              hipStream_t stream) {
    const float* X  = (const float*)d_in[0];
    const int*   ei = (const int*)d_in[1];
    const float* ew = (const float*)d_in[2];
    const float* cw = (const float*)d_in[3];
    const float* cb = (const float*)d_in[4];
    const float* wc = (const float*)d_in[5];
    const float* bg = (const float*)d_in[6];
    int N = in_sizes[0] / 32;
    int E = in_sizes[2];
    int L = in_sizes[3] / (8 * 32 * 32);
    float* out = (float*)d_out;
    int NB = (N + 255) >> 8;

    char* p = (char*)d_ws;
    auto alloc = [&](size_t bytes) -> char* {
        char* r = p; p += (bytes + 255) & ~(size_t)255; return r;
    };
    int*   bhist     = (int*)alloc((size_t)NB * 4);
    int*   bbase     = (int*)alloc((size_t)(NB + 1) * 4);
    int*   bfill     = (int*)alloc((size_t)NB * 4);
    int*   row_start = (int*)alloc((size_t)(N + 1) * 4);
    float* dinv      = (float*)alloc((size_t)N * 4);
    int2*  ebuf      = (int2*)alloc((size_t)E * 8);
    int2*  csr       = (int2*)alloc((size_t)E * 8);
    float* Y         = (float*)alloc((size_t)N * 32 * 4);
    float* AX        = (float*)alloc((size_t)N * 32 * 4);

    hipMemsetAsync(bhist, 0, (size_t)NB * 4, stream);
    k_bhist<<<512, 256, 0, stream>>>(ei, bhist, E, NB);
    k_bscan<<<1, 256, 0, stream>>>(bhist, bbase, bfill, row_start, NB, N, E);
    int nBin = (E + 4095) / 4096;
    k_bin<<<nBin, 256, 0, stream>>>(ei, ew, bfill, ebuf, E, NB);
    k_bucket<<<NB, 256, 0, stream>>>(ebuf, bbase, csr, row_start, dinv,
                                     (const float4*)X, (float4*)Y, N, E);

    for (int l = 0; l < L; l++) {
        k_gather<<<(N + 3) / 4, 256, 0, stream>>>((const float4*)Y, row_start, csr,
                                                  dinv, (float4*)AX, N);
        k_gates<<<(N + 31) / 32, 256, 0, stream>>>(AX, cw, cb, wc, bg, dinv,
                                                   out, Y, N, l, l == L - 1);
    }
}